// Round 1
// baseline (326.288 us; speedup 1.0000x reference)
//
#include <hip/hip_runtime.h>
#include <stdint.h>

// DCNv2 forward, fixed shapes: N=8, Cin=Cout=256, H=W=Ho=Wo=64, K=3x3, DG=1,
// stride=1, pad=1, dil=1.
//
// Strategy: fused implicit-im2col GEMM.
//   grid = N*Ho = 512 blocks, 256 threads (4 waves).
//   Block handles one (n, ho): all 64 wo positions x all 256 Cout.
//   K_gemm = Cin*9 = 2304, processed in 8 chunks of (32 ch x 9 taps) = 288.
//   Phase A: bilinear-sample col chunk (f32 math) -> bf16 -> LDS (B-frag layout).
//   Phase B: mfma_f32_16x16x32_bf16, A-frags from pre-swizzled bf16 weight in ws.

#define XH 64
#define XW 64
#define CIN 256
#define COUT 256
#define NK 9

typedef __attribute__((ext_vector_type(8))) short short8;   // 8 bf16 (4 VGPRs)
typedef __attribute__((ext_vector_type(4))) float floatx4;
typedef __attribute__((ext_vector_type(4))) int   intx4;

__device__ __forceinline__ short f32_to_bf16_rne(float f) {
    union { float f; uint32_t u; } v; v.f = f;
    uint32_t u = v.u;
    uint32_t r = (u + 0x7FFFu + ((u >> 16) & 1u)) >> 16;
    return (short)(uint16_t)r;
}

// ---------------------------------------------------------------------------
// Weight pre-swizzle: W3[cc][ks][mt][lane][j] = W[co][c][tap]  (bf16)
//   co = mt*16 + (lane&15); c = cc*32 + (lane>>4)*8 + j; tap = ks
// so an A-fragment load is one coalesced 16B load per lane.
// total elems = 8*9*16*64*8 = 589824
__global__ void dcn_wprep(const float* __restrict__ w, short* __restrict__ w3) {
    int idx = blockIdx.x * 256 + threadIdx.x;
    if (idx >= 8 * 9 * 16 * 64 * 8) return;
    int j    = idx & 7;
    int lane = (idx >> 3) & 63;
    int mt   = (idx >> 9) & 15;
    int t    = idx >> 13;        // cc*9 + ks, 0..71
    int ks   = t % 9;
    int cc   = t / 9;
    int co = mt * 16 + (lane & 15);
    int c  = cc * 32 + (lane >> 4) * 8 + j;
    w3[idx] = f32_to_bf16_rne(w[(co * CIN + c) * NK + ks]);
}

// ---------------------------------------------------------------------------
__launch_bounds__(256, 2)
__global__ void dcn_fused(const float* __restrict__ x,
                          const float* __restrict__ off,
                          const float* __restrict__ msk,
                          const short* __restrict__ w3,
                          const float* __restrict__ bias,
                          float* __restrict__ out) {
    // LDS: col chunk in B-fragment-major layout:
    //   colF[chunk16][8] where chunk16 = (tap*4 + quad)*64 + pos  (2304 chunks)
    __shared__ short  colF[2304 * 8];        // 36864 B
    __shared__ floatx4 pairW[576];           //  9216 B  (w00,w01,w10,w11; mask folded)
    __shared__ intx4   pairO[576];           //  9216 B  (flat y*64+x for 4 corners)

    const int bid = blockIdx.x;
    const int n  = bid >> 6;
    const int ho = bid & 63;
    const int tid  = threadIdx.x;
    const int wave = tid >> 6;
    const int lane = tid & 63;

    // ---- precompute bilinear params for 576 (wo, tap) pairs ----
    for (int p = tid; p < 576; p += 256) {
        int wo = p & 63, k = p >> 6;
        int obase = ((n * 18 + 2 * k) * XH + ho) * XW + wo;
        float dy = off[obase];
        float dx = off[obase + XH * XW];
        float mm = msk[((n * NK + k) * XH + ho) * XW + wo];
        float y  = (float)(ho - 1 + k / 3) + dy;
        float xs = (float)(wo - 1 + k % 3) + dx;
        float y0f = floorf(y), x0f = floorf(xs);
        float fy = y - y0f, fx = xs - x0f;
        int y0 = (int)y0f, x0 = (int)x0f;
        float vy0 = (y0 >= 0  && y0 < XH)     ? 1.f : 0.f;
        float vy1 = (y0 >= -1 && y0 < XH - 1) ? 1.f : 0.f;
        float vx0 = (x0 >= 0  && x0 < XW)     ? 1.f : 0.f;
        float vx1 = (x0 >= -1 && x0 < XW - 1) ? 1.f : 0.f;
        floatx4 wv;
        wv.x = (1.f - fy) * (1.f - fx) * mm * vy0 * vx0;
        wv.y = (1.f - fy) * fx         * mm * vy0 * vx1;
        wv.z = fy         * (1.f - fx) * mm * vy1 * vx0;
        wv.w = fy         * fx         * mm * vy1 * vx1;
        int y0c = min(max(y0, 0), XH - 1), y1c = min(max(y0 + 1, 0), XH - 1);
        int x0c = min(max(x0, 0), XW - 1), x1c = min(max(x0 + 1, 0), XW - 1);
        intx4 ov;
        ov.x = y0c * XW + x0c; ov.y = y0c * XW + x1c;
        ov.z = y1c * XW + x0c; ov.w = y1c * XW + x1c;
        pairW[p] = wv;
        pairO[p] = ov;
    }
    __syncthreads();

    floatx4 acc[4][4];
#pragma unroll
    for (int mt = 0; mt < 4; ++mt)
#pragma unroll
        for (int nt = 0; nt < 4; ++nt)
            acc[mt][nt] = (floatx4)(0.f);

    const float* xn = x + (size_t)n * CIN * (XH * XW);
    const short8* w3v = (const short8*)w3;

    for (int cc = 0; cc < 8; ++cc) {
        __syncthreads();   // previous GEMM phase done reading colF
        // ---- Phase A: sample 64pos x 9tap x 32ch into LDS (bf16) ----
        // item = it*256+tid: pos = item&63, r = item>>6 (0..35): k=r>>2, csub=r&3
        for (int it = 0; it < 9; ++it) {
            int item = it * 256 + tid;
            int pos  = item & 63;
            int r    = item >> 6;
            int k    = r >> 2;
            int csub = r & 3;
            int p = k * 64 + pos;
            floatx4 wv = pairW[p];
            intx4   ov = pairO[p];
            const float* xc = xn + (size_t)(cc * 32 + csub * 8) * (XH * XW);
            short8 pk;
#pragma unroll
            for (int i = 0; i < 8; ++i) {
                const float* xp = xc + i * (XH * XW);
                float v = wv.x * xp[ov.x] + wv.y * xp[ov.y] +
                          wv.z * xp[ov.z] + wv.w * xp[ov.w];
                pk[i] = f32_to_bf16_rne(v);
            }
            *(short8*)&colF[(((k * 4 + csub) * 64) + pos) * 8] = pk;
        }
        __syncthreads();

        // ---- Phase B: GEMM on the chunk: 9 K-steps of 32 ----
        const int quad = lane >> 4, cl = lane & 15;
        for (int ks = 0; ks < 9; ++ks) {
            short8 afrag[4];
#pragma unroll
            for (int mt = 0; mt < 4; ++mt) {
                int mtg = wave * 4 + mt;
                afrag[mt] = w3v[(((cc * 9 + ks) * 16 + mtg) * 64) + lane];
            }
            short8 bfrag[4];
#pragma unroll
            for (int nt = 0; nt < 4; ++nt)
                bfrag[nt] = *(const short8*)
                    &colF[(((ks * 4 + quad) * 64) + nt * 16 + cl) * 8];
#pragma unroll
            for (int mt = 0; mt < 4; ++mt)
#pragma unroll
                for (int nt = 0; nt < 4; ++nt)
                    acc[mt][nt] = __builtin_amdgcn_mfma_f32_16x16x32_bf16(
                        afrag[mt], bfrag[nt], acc[mt][nt], 0, 0, 0);
        }
    }

    // ---- epilogue: D layout col=lane&15 (pos), row=(lane>>4)*4+reg (co) ----
    const int quad = lane >> 4, cl = lane & 15;
#pragma unroll
    for (int mt = 0; mt < 4; ++mt) {
        int cobase = (wave * 4 + mt) * 16 + quad * 4;
#pragma unroll
        for (int r = 0; r < 4; ++r) {
            int co = cobase + r;
            float b = bias[co];
            float* op = out + (((size_t)n * COUT + co) * XH + ho) * XW;
#pragma unroll
            for (int nt = 0; nt < 4; ++nt)
                op[nt * 16 + cl] = acc[mt][nt][r] + b;
        }
    }
}

// ---------------------------------------------------------------------------
// Naive fallback (only if ws too small for the 1.13MB weight swizzle).
__global__ void dcn_naive(const float* __restrict__ x,
                          const float* __restrict__ off,
                          const float* __restrict__ msk,
                          const float* __restrict__ w,
                          const float* __restrict__ bias,
                          float* __restrict__ out) {
    int idx = blockIdx.x * 256 + threadIdx.x;   // N*COUT*HO*WO
    if (idx >= 8 * COUT * XH * XW) return;
    int wo = idx & 63, ho = (idx >> 6) & 63, co = (idx >> 12) & 255, n = idx >> 20;
    float acc = bias[co];
    for (int k = 0; k < NK; ++k) {
        int obase = ((n * 18 + 2 * k) * XH + ho) * XW + wo;
        float dy = off[obase];
        float dx = off[obase + XH * XW];
        float mm = msk[((n * NK + k) * XH + ho) * XW + wo];
        float y  = (float)(ho - 1 + k / 3) + dy;
        float xs = (float)(wo - 1 + k % 3) + dx;
        float y0f = floorf(y), x0f = floorf(xs);
        float fy = y - y0f, fx = xs - x0f;
        int y0 = (int)y0f, x0 = (int)x0f;
        float vy0 = (y0 >= 0  && y0 < XH)     ? 1.f : 0.f;
        float vy1 = (y0 >= -1 && y0 < XH - 1) ? 1.f : 0.f;
        float vx0 = (x0 >= 0  && x0 < XW)     ? 1.f : 0.f;
        float vx1 = (x0 >= -1 && x0 < XW - 1) ? 1.f : 0.f;
        float w00 = (1.f - fy) * (1.f - fx) * mm * vy0 * vx0;
        float w01 = (1.f - fy) * fx         * mm * vy0 * vx1;
        float w10 = fy         * (1.f - fx) * mm * vy1 * vx0;
        float w11 = fy         * fx         * mm * vy1 * vx1;
        int y0c = min(max(y0, 0), XH - 1), y1c = min(max(y0 + 1, 0), XH - 1);
        int x0c = min(max(x0, 0), XW - 1), x1c = min(max(x0 + 1, 0), XW - 1);
        int o00 = y0c * XW + x0c, o01 = y0c * XW + x1c;
        int o10 = y1c * XW + x0c, o11 = y1c * XW + x1c;
        for (int c = 0; c < CIN; ++c) {
            const float* xp = x + ((size_t)(n * CIN + c)) * (XH * XW);
            float v = w00 * xp[o00] + w01 * xp[o01] + w10 * xp[o10] + w11 * xp[o11];
            acc += v * w[(co * CIN + c) * NK + k];
        }
    }
    out[idx] = acc;
}

// ---------------------------------------------------------------------------
extern "C" void kernel_launch(void* const* d_in, const int* in_sizes, int n_in,
                              void* d_out, int out_size, void* d_ws, size_t ws_size,
                              hipStream_t stream) {
    const float* x    = (const float*)d_in[0];
    const float* off  = (const float*)d_in[1];
    const float* msk  = (const float*)d_in[2];
    const float* w    = (const float*)d_in[3];
    const float* bias = (const float*)d_in[4];
    float* out = (float*)d_out;

    const size_t W3_BYTES = (size_t)8 * 9 * 16 * 64 * 8 * sizeof(short); // 1179648
    if (ws_size >= W3_BYTES) {
        short* w3 = (short*)d_ws;
        dcn_wprep<<<(8 * 9 * 16 * 64 * 8 + 255) / 256, 256, 0, stream>>>(w, w3);
        dcn_fused<<<8 * 64, 256, 0, stream>>>(x, off, msk, w3, bias, out);
    } else {
        dcn_naive<<<(8 * COUT * XH * XW + 255) / 256, 256, 0, stream>>>(
            x, off, msk, w, bias, out);
    }
}

// Round 2
// 200.430 us; speedup vs baseline: 1.6279x; 1.6279x over previous
//
#include <hip/hip_runtime.h>
#include <stdint.h>

// DCNv2 forward, fixed shapes: N=8, Cin=Cout=256, H=W=Ho=Wo=64, K=3x3, DG=1,
// stride=1, pad=1, dil=1.
//
// R2 strategy: NHWC bf16 pre-transpose of x so bilinear gathers are
// channel-contiguous 16B vector loads; fused implicit-im2col GEMM chunked by
// tap (1 tap x 256ch per chunk); 512 thr/block for 16 waves/CU.

#define XH 64
#define XW 64
#define CIN 256
#define COUT 256
#define NK 9

typedef __attribute__((ext_vector_type(8))) short short8;   // 8 bf16 (4 VGPRs)
typedef __attribute__((ext_vector_type(4))) float floatx4;
typedef __attribute__((ext_vector_type(4))) int   intx4;

__device__ __forceinline__ short f32_to_bf16_rne(float f) {
    union { float f; uint32_t u; } v; v.f = f;
    uint32_t u = v.u;
    uint32_t r = (u + 0x7FFFu + ((u >> 16) & 1u)) >> 16;
    return (short)(uint16_t)r;
}
__device__ __forceinline__ float bf16_to_f32(short s) {
    union { uint32_t u; float f; } v;
    v.u = ((uint32_t)(uint16_t)s) << 16;
    return v.f;
}

// ---------------------------------------------------------------------------
// x (N,C,H,W) f32  ->  xT (N,H,W,C) bf16.  512 blocks (n,h), 256 threads.
// thread (chg=t&31, w0=t>>5): loops 8 w's, reads 8 scalar f32 (L1-reuses the
// 256B row across lanes/iters), writes one coalesced 16B granule per w.
__global__ void dcn_xprep(const float* __restrict__ x, short* __restrict__ xT) {
    int bid = blockIdx.x;
    int n = bid >> 6, h = bid & 63;
    int t = threadIdx.x;
    int chg = t & 31, w0 = t >> 5;
    const float* xb = x + ((size_t)n * CIN) * (XH * XW) + h * XW;
    short8* ob = (short8*)(xT + ((size_t)(n * XH + h)) * (XW * CIN));
    for (int i = 0; i < 8; ++i) {
        int w = w0 * 8 + i;
        short8 pk;
#pragma unroll
        for (int j = 0; j < 8; ++j) {
            float v = xb[(size_t)(chg * 8 + j) * (XH * XW) + w];
            pk[j] = f32_to_bf16_rne(v);
        }
        ob[w * 32 + chg] = pk;
    }
}

// ---------------------------------------------------------------------------
// Weight pre-swizzle: w3 element (((k*8+ks)*16+mt)*64+lane)*8+j = W[co][c][k]
//   co = mt*16 + (lane&15); c = ks*32 + (lane>>4)*8 + j; tap = k
// total elems = 9*8*16*64*8 = 589824 (1.18 MB bf16)
__global__ void dcn_wprep(const float* __restrict__ w, short* __restrict__ w3) {
    int idx = blockIdx.x * 256 + threadIdx.x;
    if (idx >= 9 * 8 * 16 * 64 * 8) return;
    int j    = idx & 7;
    int lane = (idx >> 3) & 63;
    int mt   = (idx >> 9) & 15;
    int t    = idx >> 13;        // k*8 + ks, 0..71
    int ks   = t & 7;
    int k    = t >> 3;
    int co = mt * 16 + (lane & 15);
    int c  = ks * 32 + (lane >> 4) * 8 + j;
    w3[idx] = f32_to_bf16_rne(w[(co * CIN + c) * NK + k]);
}

// ---------------------------------------------------------------------------
// Fused kernel. grid = N*Ho = 512, 512 threads (8 waves).
// Per tap k: phase A samples 64pos x 256ch (bf16, NHWC gathers) -> colF LDS;
// phase B: 8 K-steps of mfma_f32_16x16x32_bf16, A from w3 (L2), B from colF.
__launch_bounds__(512, 4)
__global__ void dcn_fused2(const short* __restrict__ xT,
                           const float* __restrict__ off,
                           const float* __restrict__ msk,
                           const short* __restrict__ w3,
                           const float* __restrict__ bias,
                           float* __restrict__ out) {
    // colF: 2048 granules of 16B. granule(chg,pos) at g = chg*64 + (pos^(chg&7))
    __shared__ short   colF[2048 * 8];       // 32768 B
    __shared__ floatx4 pairW[576];           //  9216 B
    __shared__ intx4   pairO[576];           //  9216 B

    const int bid = blockIdx.x;
    const int n  = bid >> 6;
    const int ho = bid & 63;
    const int tid  = threadIdx.x;
    const int wave = tid >> 6;
    const int lane = tid & 63;

    // ---- bilinear params for 576 (wo, tap) pairs (mask folded into weights) --
    for (int p = tid; p < 576; p += 512) {
        int wo = p & 63, k = p >> 6;
        int obase = ((n * 18 + 2 * k) * XH + ho) * XW + wo;
        float dy = off[obase];
        float dx = off[obase + XH * XW];
        float mm = msk[((n * NK + k) * XH + ho) * XW + wo];
        float y  = (float)(ho - 1 + k / 3) + dy;
        float xs = (float)(wo - 1 + k % 3) + dx;
        float y0f = floorf(y), x0f = floorf(xs);
        float fy = y - y0f, fx = xs - x0f;
        int y0 = (int)y0f, x0 = (int)x0f;
        float vy0 = (y0 >= 0  && y0 < XH)     ? 1.f : 0.f;
        float vy1 = (y0 >= -1 && y0 < XH - 1) ? 1.f : 0.f;
        float vx0 = (x0 >= 0  && x0 < XW)     ? 1.f : 0.f;
        float vx1 = (x0 >= -1 && x0 < XW - 1) ? 1.f : 0.f;
        floatx4 wv;
        wv.x = (1.f - fy) * (1.f - fx) * mm * vy0 * vx0;
        wv.y = (1.f - fy) * fx         * mm * vy0 * vx1;
        wv.z = fy         * (1.f - fx) * mm * vy1 * vx0;
        wv.w = fy         * fx         * mm * vy1 * vx1;
        int y0c = min(max(y0, 0), XH - 1), y1c = min(max(y0 + 1, 0), XH - 1);
        int x0c = min(max(x0, 0), XW - 1), x1c = min(max(x0 + 1, 0), XW - 1);
        intx4 ov;
        ov.x = y0c * XW + x0c; ov.y = y0c * XW + x1c;
        ov.z = y1c * XW + x0c; ov.w = y1c * XW + x1c;
        pairW[p] = wv;
        pairO[p] = ov;
    }
    __syncthreads();

    floatx4 acc[2][4];
#pragma unroll
    for (int mt = 0; mt < 2; ++mt)
#pragma unroll
        for (int nt = 0; nt < 4; ++nt)
            acc[mt][nt] = (floatx4)(0.f);

    const short8* xTv = (const short8*)(xT + (size_t)n * (XH * XW * CIN));
    const short8* w3v = (const short8*)w3;
    const int quad = lane >> 4, cl = lane & 15;

    for (int k = 0; k < NK; ++k) {
        if (k) __syncthreads();    // phase B of tap k-1 done reading colF
        // ---- Phase A: 2048 items = (pos, chg). lanes 0..31 = 32 chg of one
        // pos -> global loads are 512B-contiguous per corner.
        for (int it = 0; it < 4; ++it) {
            int idx = it * 512 + tid;
            int chg = idx & 31;
            int pos = idx >> 5;
            int p = k * 64 + pos;
            floatx4 wv = pairW[p];
            intx4   ov = pairO[p];
            short8 s00 = xTv[(size_t)ov.x * 32 + chg];
            short8 s01 = xTv[(size_t)ov.y * 32 + chg];
            short8 s10 = xTv[(size_t)ov.z * 32 + chg];
            short8 s11 = xTv[(size_t)ov.w * 32 + chg];
            short8 pk;
#pragma unroll
            for (int i = 0; i < 8; ++i) {
                float v = wv.x * bf16_to_f32(s00[i]) + wv.y * bf16_to_f32(s01[i]) +
                          wv.z * bf16_to_f32(s10[i]) + wv.w * bf16_to_f32(s11[i]);
                pk[i] = f32_to_bf16_rne(v);
            }
            int g = chg * 64 + (pos ^ (chg & 7));
            *(short8*)&colF[g * 8] = pk;
        }
        __syncthreads();

        // ---- Phase B: 8 K-steps of 32 channels ----
        for (int ks = 0; ks < 8; ++ks) {
            short8 afrag[2];
#pragma unroll
            for (int mt = 0; mt < 2; ++mt)
                afrag[mt] = w3v[(((k * 8 + ks) * 16) + (wave * 2 + mt)) * 64 + lane];
            short8 bfrag[4];
            int cr = ks * 4 + quad;      // chg being read
            int gb = cr * 64, sw = cr & 7;
#pragma unroll
            for (int nt = 0; nt < 4; ++nt)
                bfrag[nt] = *(const short8*)&colF[(gb + ((nt * 16 + cl) ^ sw)) * 8];
#pragma unroll
            for (int mt = 0; mt < 2; ++mt)
#pragma unroll
                for (int nt = 0; nt < 4; ++nt)
                    acc[mt][nt] = __builtin_amdgcn_mfma_f32_16x16x32_bf16(
                        afrag[mt], bfrag[nt], acc[mt][nt], 0, 0, 0);
        }
    }

    // ---- epilogue: D layout col=lane&15 (pos), row=(lane>>4)*4+reg (co) ----
#pragma unroll
    for (int mt = 0; mt < 2; ++mt) {
        int cobase = (wave * 2 + mt) * 16 + quad * 4;
#pragma unroll
        for (int r = 0; r < 4; ++r) {
            int co = cobase + r;
            float b = bias[co];
            float* op = out + (((size_t)n * COUT + co) * XH + ho) * XW;
#pragma unroll
            for (int nt = 0; nt < 4; ++nt)
                op[nt * 16 + cl] = acc[mt][nt][r] + b;
        }
    }
}

// ===========================================================================
// Fallback 1 (ws in [1.18MB, 18MB)): round-1 fused kernel (NCHW gathers).
__global__ void dcn_wprep_v1(const float* __restrict__ w, short* __restrict__ w3) {
    int idx = blockIdx.x * 256 + threadIdx.x;
    if (idx >= 8 * 9 * 16 * 64 * 8) return;
    int j    = idx & 7;
    int lane = (idx >> 3) & 63;
    int mt   = (idx >> 9) & 15;
    int t    = idx >> 13;
    int ks   = t % 9;
    int cc   = t / 9;
    int co = mt * 16 + (lane & 15);
    int c  = cc * 32 + (lane >> 4) * 8 + j;
    w3[idx] = f32_to_bf16_rne(w[(co * CIN + c) * NK + ks]);
}

__launch_bounds__(256, 2)
__global__ void dcn_fused_v1(const float* __restrict__ x,
                             const float* __restrict__ off,
                             const float* __restrict__ msk,
                             const short* __restrict__ w3,
                             const float* __restrict__ bias,
                             float* __restrict__ out) {
    __shared__ short  colF[2304 * 8];
    __shared__ floatx4 pairW[576];
    __shared__ intx4   pairO[576];

    const int bid = blockIdx.x;
    const int n  = bid >> 6;
    const int ho = bid & 63;
    const int tid  = threadIdx.x;
    const int wave = tid >> 6;
    const int lane = tid & 63;

    for (int p = tid; p < 576; p += 256) {
        int wo = p & 63, k = p >> 6;
        int obase = ((n * 18 + 2 * k) * XH + ho) * XW + wo;
        float dy = off[obase];
        float dx = off[obase + XH * XW];
        float mm = msk[((n * NK + k) * XH + ho) * XW + wo];
        float y  = (float)(ho - 1 + k / 3) + dy;
        float xs = (float)(wo - 1 + k % 3) + dx;
        float y0f = floorf(y), x0f = floorf(xs);
        float fy = y - y0f, fx = xs - x0f;
        int y0 = (int)y0f, x0 = (int)x0f;
        float vy0 = (y0 >= 0  && y0 < XH)     ? 1.f : 0.f;
        float vy1 = (y0 >= -1 && y0 < XH - 1) ? 1.f : 0.f;
        float vx0 = (x0 >= 0  && x0 < XW)     ? 1.f : 0.f;
        float vx1 = (x0 >= -1 && x0 < XW - 1) ? 1.f : 0.f;
        floatx4 wv;
        wv.x = (1.f - fy) * (1.f - fx) * mm * vy0 * vx0;
        wv.y = (1.f - fy) * fx         * mm * vy0 * vx1;
        wv.z = fy         * (1.f - fx) * mm * vy1 * vx0;
        wv.w = fy         * fx         * mm * vy1 * vx1;
        int y0c = min(max(y0, 0), XH - 1), y1c = min(max(y0 + 1, 0), XH - 1);
        int x0c = min(max(x0, 0), XW - 1), x1c = min(max(x0 + 1, 0), XW - 1);
        intx4 ov;
        ov.x = y0c * XW + x0c; ov.y = y0c * XW + x1c;
        ov.z = y1c * XW + x0c; ov.w = y1c * XW + x1c;
        pairW[p] = wv;
        pairO[p] = ov;
    }
    __syncthreads();

    floatx4 acc[4][4];
#pragma unroll
    for (int mt = 0; mt < 4; ++mt)
#pragma unroll
        for (int nt = 0; nt < 4; ++nt)
            acc[mt][nt] = (floatx4)(0.f);

    const float* xn = x + (size_t)n * CIN * (XH * XW);
    const short8* w3v = (const short8*)w3;

    for (int cc = 0; cc < 8; ++cc) {
        __syncthreads();
        for (int it = 0; it < 9; ++it) {
            int item = it * 256 + tid;
            int pos  = item & 63;
            int r    = item >> 6;
            int k    = r >> 2;
            int csub = r & 3;
            int p = k * 64 + pos;
            floatx4 wv = pairW[p];
            intx4   ov = pairO[p];
            const float* xc = xn + (size_t)(cc * 32 + csub * 8) * (XH * XW);
            short8 pk;
#pragma unroll
            for (int i = 0; i < 8; ++i) {
                const float* xp = xc + i * (XH * XW);
                float v = wv.x * xp[ov.x] + wv.y * xp[ov.y] +
                          wv.z * xp[ov.z] + wv.w * xp[ov.w];
                pk[i] = f32_to_bf16_rne(v);
            }
            *(short8*)&colF[(((k * 4 + csub) * 64) + pos) * 8] = pk;
        }
        __syncthreads();

        const int quad = lane >> 4, cl = lane & 15;
        for (int ks = 0; ks < 9; ++ks) {
            short8 afrag[4];
#pragma unroll
            for (int mt = 0; mt < 4; ++mt) {
                int mtg = wave * 4 + mt;
                afrag[mt] = w3v[(((cc * 9 + ks) * 16 + mtg) * 64) + lane];
            }
            short8 bfrag[4];
#pragma unroll
            for (int nt = 0; nt < 4; ++nt)
                bfrag[nt] = *(const short8*)
                    &colF[(((ks * 4 + quad) * 64) + nt * 16 + cl) * 8];
#pragma unroll
            for (int mt = 0; mt < 4; ++mt)
#pragma unroll
                for (int nt = 0; nt < 4; ++nt)
                    acc[mt][nt] = __builtin_amdgcn_mfma_f32_16x16x32_bf16(
                        afrag[mt], bfrag[nt], acc[mt][nt], 0, 0, 0);
        }
    }

    const int quad = lane >> 4, cl = lane & 15;
#pragma unroll
    for (int mt = 0; mt < 4; ++mt) {
        int cobase = (wave * 4 + mt) * 16 + quad * 4;
#pragma unroll
        for (int r = 0; r < 4; ++r) {
            int co = cobase + r;
            float b = bias[co];
            float* op = out + (((size_t)n * COUT + co) * XH + ho) * XW;
#pragma unroll
            for (int nt = 0; nt < 4; ++nt)
                op[nt * 16 + cl] = acc[mt][nt][r] + b;
        }
    }
}

// Fallback 2: naive (ws < 1.18MB).
__global__ void dcn_naive(const float* __restrict__ x,
                          const float* __restrict__ off,
                          const float* __restrict__ msk,
                          const float* __restrict__ w,
                          const float* __restrict__ bias,
                          float* __restrict__ out) {
    int idx = blockIdx.x * 256 + threadIdx.x;
    if (idx >= 8 * COUT * XH * XW) return;
    int wo = idx & 63, ho = (idx >> 6) & 63, co = (idx >> 12) & 255, n = idx >> 20;
    float acc = bias[co];
    for (int k = 0; k < NK; ++k) {
        int obase = ((n * 18 + 2 * k) * XH + ho) * XW + wo;
        float dy = off[obase];
        float dx = off[obase + XH * XW];
        float mm = msk[((n * NK + k) * XH + ho) * XW + wo];
        float y  = (float)(ho - 1 + k / 3) + dy;
        float xs = (float)(wo - 1 + k % 3) + dx;
        float y0f = floorf(y), x0f = floorf(xs);
        float fy = y - y0f, fx = xs - x0f;
        int y0 = (int)y0f, x0 = (int)x0f;
        float vy0 = (y0 >= 0  && y0 < XH)     ? 1.f : 0.f;
        float vy1 = (y0 >= -1 && y0 < XH - 1) ? 1.f : 0.f;
        float vx0 = (x0 >= 0  && x0 < XW)     ? 1.f : 0.f;
        float vx1 = (x0 >= -1 && x0 < XW - 1) ? 1.f : 0.f;
        float w00 = (1.f - fy) * (1.f - fx) * mm * vy0 * vx0;
        float w01 = (1.f - fy) * fx         * mm * vy0 * vx1;
        float w10 = fy         * (1.f - fx) * mm * vy1 * vx0;
        float w11 = fy         * fx         * mm * vy1 * vx1;
        int y0c = min(max(y0, 0), XH - 1), y1c = min(max(y0 + 1, 0), XH - 1);
        int x0c = min(max(x0, 0), XW - 1), x1c = min(max(x0 + 1, 0), XW - 1);
        int o00 = y0c * XW + x0c, o01 = y0c * XW + x1c;
        int o10 = y1c * XW + x0c, o11 = y1c * XW + x1c;
        for (int c = 0; c < CIN; ++c) {
            const float* xp = x + ((size_t)(n * CIN + c)) * (XH * XW);
            float v = w00 * xp[o00] + w01 * xp[o01] + w10 * xp[o10] + w11 * xp[o11];
            acc += v * w[(co * CIN + c) * NK + k];
        }
    }
    out[idx] = acc;
}

// ---------------------------------------------------------------------------
extern "C" void kernel_launch(void* const* d_in, const int* in_sizes, int n_in,
                              void* d_out, int out_size, void* d_ws, size_t ws_size,
                              hipStream_t stream) {
    const float* x    = (const float*)d_in[0];
    const float* off  = (const float*)d_in[1];
    const float* msk  = (const float*)d_in[2];
    const float* w    = (const float*)d_in[3];
    const float* bias = (const float*)d_in[4];
    float* out = (float*)d_out;

    const size_t W3_BYTES = (size_t)9 * 8 * 16 * 64 * 8 * sizeof(short); // 1179648
    const size_t XT_BYTES = (size_t)8 * XH * XW * CIN * sizeof(short);   // 16777216

    if (ws_size >= W3_BYTES + XT_BYTES) {
        short* w3 = (short*)d_ws;
        short* xT = (short*)((char*)d_ws + W3_BYTES);
        dcn_wprep<<<(9 * 8 * 16 * 64 * 8 + 255) / 256, 256, 0, stream>>>(w, w3);
        dcn_xprep<<<8 * XH, 256, 0, stream>>>(x, xT);
        dcn_fused2<<<8 * 64, 512, 0, stream>>>(xT, off, msk, w3, bias, out);
    } else if (ws_size >= W3_BYTES) {
        short* w3 = (short*)d_ws;
        dcn_wprep_v1<<<(8 * 9 * 16 * 64 * 8 + 255) / 256, 256, 0, stream>>>(w, w3);
        dcn_fused_v1<<<8 * 64, 256, 0, stream>>>(x, off, msk, w3, bias, out);
    } else {
        dcn_naive<<<(8 * COUT * XH * XW + 255) / 256, 256, 0, stream>>>(
            x, off, msk, w, bias, out);
    }
}

// Round 3
// 153.696 us; speedup vs baseline: 2.1229x; 1.3041x over previous
//
#include <hip/hip_runtime.h>
#include <hip/hip_bf16.h>
#include <stdint.h>

// DCNv2 forward, fixed shapes: N=8, Cin=Cout=256, H=W=Ho=Wo=64, K=3x3, DG=1,
// stride=1, pad=1, dil=1.
//
// R3: XCD-aware swizzle (each XCD owns an 8-row ho band -> xT rows + w3 stay
// L2-resident; xprep writes rows from the SAME XCD that consumes them),
// coalesced register-repack xprep fused with wprep, packed f32 bilinear math.

#define XH 64
#define XW 64
#define CIN 256
#define COUT 256
#define NK 9

typedef __attribute__((ext_vector_type(8))) short short8;   // 8 bf16 (4 VGPRs)
typedef __attribute__((ext_vector_type(4))) float floatx4;
typedef __attribute__((ext_vector_type(2))) float floatx2;
typedef __attribute__((ext_vector_type(4))) int   intx4;

__device__ __forceinline__ short f32_to_bf16_rne(float f) {
    union { float f; uint32_t u; } v; v.f = f;
    uint32_t u = v.u;
    uint32_t r = (u + 0x7FFFu + ((u >> 16) & 1u)) >> 16;
    return (short)(uint16_t)r;
}
__device__ __forceinline__ float bf16_to_f32(short s) {
    union { uint32_t u; float f; } v;
    v.u = ((uint32_t)(uint16_t)s) << 16;
    return v.f;
}
__device__ __forceinline__ floatx2 bf16x2_to_f32x2(uint32_t u) {
    union { uint32_t u; float f; } lo, hi;
    lo.u = u << 16;
    hi.u = u & 0xFFFF0000u;
    floatx2 r; r.x = lo.f; r.y = hi.f;
    return r;
}

// ---------------------------------------------------------------------------
// Combined prep.
// Blocks [0,512): x (N,C,H,W) f32 -> xT (N,H,W,C) bf16, XCD-swizzled so the
//   XCD that writes rows [8x,8x+8) is the one that reads them in dcn_fused3.
//   Thread reads 8 float4 (contiguous 256B runs across 16 lanes), writes 4
//   16B granules (64B segments per wave).
// Blocks [512,800): weight swizzle -> w3 (bf16), 8 elems/thread.
//   w3[(((k*8+ks)*16+mt)*64+lane)*8+j] = W[mt*16+(lane&15)][ks*32+(lane>>4)*8+j][k]
__global__ void dcn_prep(const float* __restrict__ x, const float* __restrict__ w,
                         short* __restrict__ xT, short* __restrict__ w3) {
    int b = blockIdx.x;
    int tid = threadIdx.x;
    if (b < 512) {
        int xcd = b & 7, slot = b >> 3;
        int h = xcd * 8 + (slot & 7);
        int n = slot >> 3;
        int q = tid & 15;        // w-quad
        int cgh = tid >> 4;      // 0..15
        short8* ob = (short8*)(xT + ((size_t)(n * XH + h)) * (XW * CIN));
        for (int it = 0; it < 2; ++it) {
            int cg = cgh + it * 16;          // channel granule 0..31
            const float* xb = x + ((size_t)(n * CIN + cg * 8)) * (XH * XW)
                                + h * XW + q * 4;
            floatx4 r[8];
#pragma unroll
            for (int j = 0; j < 8; ++j)
                r[j] = *(const floatx4*)(xb + (size_t)j * (XH * XW));
#pragma unroll
            for (int jw = 0; jw < 4; ++jw) {
                short8 pk;
#pragma unroll
                for (int j = 0; j < 8; ++j) pk[j] = f32_to_bf16_rne(r[j][jw]);
                ob[(q * 4 + jw) * 32 + cg] = pk;
            }
        }
    } else {
        int gidx = (b - 512) * 256 + tid;    // granule index, < 73728
        int lane = gidx & 63;
        int mt   = (gidx >> 6) & 15;
        int t    = gidx >> 10;               // k*8 + ks
        int ks   = t & 7;
        int k    = t >> 3;
        int co = mt * 16 + (lane & 15);
        int c0 = ks * 32 + (lane >> 4) * 8;
        short8 pk;
#pragma unroll
        for (int j = 0; j < 8; ++j)
            pk[j] = f32_to_bf16_rne(w[(co * CIN + c0 + j) * NK + k]);
        *(short8*)&w3[(size_t)gidx * 8] = pk;
    }
}

// ---------------------------------------------------------------------------
// Fused kernel. grid = N*Ho = 512, 512 threads (8 waves). XCD-swizzled.
// Per tap k: phase A samples 64pos x 256ch (bf16 NHWC gathers, pk-f32 math)
// -> colF LDS; phase B: 8 K-steps of mfma_f32_16x16x32_bf16.
__launch_bounds__(512, 4)
__global__ void dcn_fused3(const short* __restrict__ xT,
                           const float* __restrict__ off,
                           const float* __restrict__ msk,
                           const short* __restrict__ w3,
                           const float* __restrict__ bias,
                           float* __restrict__ out) {
    // colF: 2048 granules of 16B. granule(chg,pos) at g = chg*64 + (pos^(chg&7))
    __shared__ short   colF[2048 * 8];       // 32768 B
    __shared__ floatx4 pairW[576];           //  9216 B
    __shared__ intx4   pairO[576];           //  9216 B

    const int bid = blockIdx.x;
    const int xcd = bid & 7, slot = bid >> 3;
    const int ho = xcd * 8 + (slot & 7);     // XCD x owns ho band [8x, 8x+8)
    const int n  = slot >> 3;
    const int tid  = threadIdx.x;
    const int wave = tid >> 6;
    const int lane = tid & 63;

    // ---- bilinear params for 576 (wo, tap) pairs (mask folded into weights) --
    for (int p = tid; p < 576; p += 512) {
        int wo = p & 63, k = p >> 6;
        int obase = ((n * 18 + 2 * k) * XH + ho) * XW + wo;
        float dy = off[obase];
        float dx = off[obase + XH * XW];
        float mm = msk[((n * NK + k) * XH + ho) * XW + wo];
        float y  = (float)(ho - 1 + k / 3) + dy;
        float xs = (float)(wo - 1 + k % 3) + dx;
        float y0f = floorf(y), x0f = floorf(xs);
        float fy = y - y0f, fx = xs - x0f;
        int y0 = (int)y0f, x0 = (int)x0f;
        float vy0 = (y0 >= 0  && y0 < XH)     ? 1.f : 0.f;
        float vy1 = (y0 >= -1 && y0 < XH - 1) ? 1.f : 0.f;
        float vx0 = (x0 >= 0  && x0 < XW)     ? 1.f : 0.f;
        float vx1 = (x0 >= -1 && x0 < XW - 1) ? 1.f : 0.f;
        floatx4 wv;
        wv.x = (1.f - fy) * (1.f - fx) * mm * vy0 * vx0;
        wv.y = (1.f - fy) * fx         * mm * vy0 * vx1;
        wv.z = fy         * (1.f - fx) * mm * vy1 * vx0;
        wv.w = fy         * fx         * mm * vy1 * vx1;
        int y0c = min(max(y0, 0), XH - 1), y1c = min(max(y0 + 1, 0), XH - 1);
        int x0c = min(max(x0, 0), XW - 1), x1c = min(max(x0 + 1, 0), XW - 1);
        intx4 ov;
        ov.x = y0c * XW + x0c; ov.y = y0c * XW + x1c;
        ov.z = y1c * XW + x0c; ov.w = y1c * XW + x1c;
        pairW[p] = wv;
        pairO[p] = ov;
    }
    __syncthreads();

    floatx4 acc[2][4];
#pragma unroll
    for (int mt = 0; mt < 2; ++mt)
#pragma unroll
        for (int nt = 0; nt < 4; ++nt)
            acc[mt][nt] = (floatx4)(0.f);

    const short8* xTv = (const short8*)(xT + (size_t)n * (XH * XW * CIN));
    const short8* w3v = (const short8*)w3;
    const int quad = lane >> 4, cl = lane & 15;

    union U8 { short8 s; uint32_t u[4]; };

    for (int k = 0; k < NK; ++k) {
        if (k) __syncthreads();    // phase B of tap k-1 done reading colF
        // ---- Phase A: 2048 items = (pos, chg); 32 lanes cover 32 chg of one
        // pos -> each corner load is 512B contiguous.
        for (int it = 0; it < 4; ++it) {
            int idx = it * 512 + tid;
            int chg = idx & 31;
            int pos = idx >> 5;
            int p = k * 64 + pos;
            floatx4 wv = pairW[p];
            intx4   ov = pairO[p];
            U8 s00, s01, s10, s11, pk;
            s00.s = xTv[(size_t)ov.x * 32 + chg];
            s01.s = xTv[(size_t)ov.y * 32 + chg];
            s10.s = xTv[(size_t)ov.z * 32 + chg];
            s11.s = xTv[(size_t)ov.w * 32 + chg];
#pragma unroll
            for (int i = 0; i < 4; ++i) {
                floatx2 v = bf16x2_to_f32x2(s00.u[i]) * wv.x
                          + bf16x2_to_f32x2(s01.u[i]) * wv.y
                          + bf16x2_to_f32x2(s10.u[i]) * wv.z
                          + bf16x2_to_f32x2(s11.u[i]) * wv.w;
                float2 ff; ff.x = v.x; ff.y = v.y;
                __hip_bfloat162 hb = __float22bfloat162_rn(ff);
                __builtin_memcpy(&pk.u[i], &hb, 4);
            }
            int g = chg * 64 + (pos ^ (chg & 7));
            *(short8*)&colF[g * 8] = pk.s;
        }
        __syncthreads();

        // ---- Phase B: 8 K-steps of 32 channels ----
        for (int ks = 0; ks < 8; ++ks) {
            short8 afrag[2];
#pragma unroll
            for (int mt = 0; mt < 2; ++mt)
                afrag[mt] = w3v[(((k * 8 + ks) * 16) + (wave * 2 + mt)) * 64 + lane];
            short8 bfrag[4];
            int cr = ks * 4 + quad;      // chg being read
            int gb = cr * 64, sw = cr & 7;
#pragma unroll
            for (int nt = 0; nt < 4; ++nt)
                bfrag[nt] = *(const short8*)&colF[(gb + ((nt * 16 + cl) ^ sw)) * 8];
#pragma unroll
            for (int mt = 0; mt < 2; ++mt)
#pragma unroll
                for (int nt = 0; nt < 4; ++nt)
                    acc[mt][nt] = __builtin_amdgcn_mfma_f32_16x16x32_bf16(
                        afrag[mt], bfrag[nt], acc[mt][nt], 0, 0, 0);
        }
    }

    // ---- epilogue: D layout col=lane&15 (pos), row=(lane>>4)*4+reg (co) ----
#pragma unroll
    for (int mt = 0; mt < 2; ++mt) {
        int cobase = (wave * 2 + mt) * 16 + quad * 4;
#pragma unroll
        for (int r = 0; r < 4; ++r) {
            int co = cobase + r;
            float b = bias[co];
            float* op = out + (((size_t)n * COUT + co) * XH + ho) * XW;
#pragma unroll
            for (int nt = 0; nt < 4; ++nt)
                op[nt * 16 + cl] = acc[mt][nt][r] + b;
        }
    }
}

// ===========================================================================
// Fallback 1 (ws in [1.18MB, 18MB)): round-1 fused kernel (NCHW gathers).
__global__ void dcn_wprep_v1(const float* __restrict__ w, short* __restrict__ w3) {
    int idx = blockIdx.x * 256 + threadIdx.x;
    if (idx >= 8 * 9 * 16 * 64 * 8) return;
    int j    = idx & 7;
    int lane = (idx >> 3) & 63;
    int mt   = (idx >> 9) & 15;
    int t    = idx >> 13;
    int ks   = t % 9;
    int cc   = t / 9;
    int co = mt * 16 + (lane & 15);
    int c  = cc * 32 + (lane >> 4) * 8 + j;
    w3[idx] = f32_to_bf16_rne(w[(co * CIN + c) * NK + ks]);
}

__launch_bounds__(256, 2)
__global__ void dcn_fused_v1(const float* __restrict__ x,
                             const float* __restrict__ off,
                             const float* __restrict__ msk,
                             const short* __restrict__ w3,
                             const float* __restrict__ bias,
                             float* __restrict__ out) {
    __shared__ short  colF[2304 * 8];
    __shared__ floatx4 pairW[576];
    __shared__ intx4   pairO[576];

    const int bid = blockIdx.x;
    const int n  = bid >> 6;
    const int ho = bid & 63;
    const int tid  = threadIdx.x;
    const int wave = tid >> 6;
    const int lane = tid & 63;

    for (int p = tid; p < 576; p += 256) {
        int wo = p & 63, k = p >> 6;
        int obase = ((n * 18 + 2 * k) * XH + ho) * XW + wo;
        float dy = off[obase];
        float dx = off[obase + XH * XW];
        float mm = msk[((n * NK + k) * XH + ho) * XW + wo];
        float y  = (float)(ho - 1 + k / 3) + dy;
        float xs = (float)(wo - 1 + k % 3) + dx;
        float y0f = floorf(y), x0f = floorf(xs);
        float fy = y - y0f, fx = xs - x0f;
        int y0 = (int)y0f, x0 = (int)x0f;
        float vy0 = (y0 >= 0  && y0 < XH)     ? 1.f : 0.f;
        float vy1 = (y0 >= -1 && y0 < XH - 1) ? 1.f : 0.f;
        float vx0 = (x0 >= 0  && x0 < XW)     ? 1.f : 0.f;
        float vx1 = (x0 >= -1 && x0 < XW - 1) ? 1.f : 0.f;
        floatx4 wv;
        wv.x = (1.f - fy) * (1.f - fx) * mm * vy0 * vx0;
        wv.y = (1.f - fy) * fx         * mm * vy0 * vx1;
        wv.z = fy         * (1.f - fx) * mm * vy1 * vx0;
        wv.w = fy         * fx         * mm * vy1 * vx1;
        int y0c = min(max(y0, 0), XH - 1), y1c = min(max(y0 + 1, 0), XH - 1);
        int x0c = min(max(x0, 0), XW - 1), x1c = min(max(x0 + 1, 0), XW - 1);
        intx4 ov;
        ov.x = y0c * XW + x0c; ov.y = y0c * XW + x1c;
        ov.z = y1c * XW + x0c; ov.w = y1c * XW + x1c;
        pairW[p] = wv;
        pairO[p] = ov;
    }
    __syncthreads();

    floatx4 acc[4][4];
#pragma unroll
    for (int mt = 0; mt < 4; ++mt)
#pragma unroll
        for (int nt = 0; nt < 4; ++nt)
            acc[mt][nt] = (floatx4)(0.f);

    const float* xn = x + (size_t)n * CIN * (XH * XW);
    const short8* w3v = (const short8*)w3;

    for (int cc = 0; cc < 8; ++cc) {
        __syncthreads();
        for (int it = 0; it < 9; ++it) {
            int item = it * 256 + tid;
            int pos  = item & 63;
            int r    = item >> 6;
            int k    = r >> 2;
            int csub = r & 3;
            int p = k * 64 + pos;
            floatx4 wv = pairW[p];
            intx4   ov = pairO[p];
            const float* xc = xn + (size_t)(cc * 32 + csub * 8) * (XH * XW);
            short8 pk;
#pragma unroll
            for (int i = 0; i < 8; ++i) {
                const float* xp = xc + i * (XH * XW);
                float v = wv.x * xp[ov.x] + wv.y * xp[ov.y] +
                          wv.z * xp[ov.z] + wv.w * xp[ov.w];
                pk[i] = f32_to_bf16_rne(v);
            }
            *(short8*)&colF[(((k * 4 + csub) * 64) + pos) * 8] = pk;
        }
        __syncthreads();

        const int quad = lane >> 4, cl = lane & 15;
        for (int ks = 0; ks < 9; ++ks) {
            short8 afrag[4];
#pragma unroll
            for (int mt = 0; mt < 4; ++mt) {
                int mtg = wave * 4 + mt;
                afrag[mt] = w3v[(((cc * 9 + ks) * 16 + mtg) * 64) + lane];
            }
            short8 bfrag[4];
#pragma unroll
            for (int nt = 0; nt < 4; ++nt)
                bfrag[nt] = *(const short8*)
                    &colF[(((ks * 4 + quad) * 64) + nt * 16 + cl) * 8];
#pragma unroll
            for (int mt = 0; mt < 4; ++mt)
#pragma unroll
                for (int nt = 0; nt < 4; ++nt)
                    acc[mt][nt] = __builtin_amdgcn_mfma_f32_16x16x32_bf16(
                        afrag[mt], bfrag[nt], acc[mt][nt], 0, 0, 0);
        }
    }

    const int quad = lane >> 4, cl = lane & 15;
#pragma unroll
    for (int mt = 0; mt < 4; ++mt) {
        int cobase = (wave * 4 + mt) * 16 + quad * 4;
#pragma unroll
        for (int r = 0; r < 4; ++r) {
            int co = cobase + r;
            float b = bias[co];
            float* op = out + (((size_t)n * COUT + co) * XH + ho) * XW;
#pragma unroll
            for (int nt = 0; nt < 4; ++nt)
                op[nt * 16 + cl] = acc[mt][nt][r] + b;
        }
    }
}

// Fallback 2: naive (ws < 1.18MB).
__global__ void dcn_naive(const float* __restrict__ x,
                          const float* __restrict__ off,
                          const float* __restrict__ msk,
                          const float* __restrict__ w,
                          const float* __restrict__ bias,
                          float* __restrict__ out) {
    int idx = blockIdx.x * 256 + threadIdx.x;
    if (idx >= 8 * COUT * XH * XW) return;
    int wo = idx & 63, ho = (idx >> 6) & 63, co = (idx >> 12) & 255, n = idx >> 20;
    float acc = bias[co];
    for (int k = 0; k < NK; ++k) {
        int obase = ((n * 18 + 2 * k) * XH + ho) * XW + wo;
        float dy = off[obase];
        float dx = off[obase + XH * XW];
        float mm = msk[((n * NK + k) * XH + ho) * XW + wo];
        float y  = (float)(ho - 1 + k / 3) + dy;
        float xs = (float)(wo - 1 + k % 3) + dx;
        float y0f = floorf(y), x0f = floorf(xs);
        float fy = y - y0f, fx = xs - x0f;
        int y0 = (int)y0f, x0 = (int)x0f;
        float vy0 = (y0 >= 0  && y0 < XH)     ? 1.f : 0.f;
        float vy1 = (y0 >= -1 && y0 < XH - 1) ? 1.f : 0.f;
        float vx0 = (x0 >= 0  && x0 < XW)     ? 1.f : 0.f;
        float vx1 = (x0 >= -1 && x0 < XW - 1) ? 1.f : 0.f;
        float w00 = (1.f - fy) * (1.f - fx) * mm * vy0 * vx0;
        float w01 = (1.f - fy) * fx         * mm * vy0 * vx1;
        float w10 = fy         * (1.f - fx) * mm * vy1 * vx0;
        float w11 = fy         * fx         * mm * vy1 * vx1;
        int y0c = min(max(y0, 0), XH - 1), y1c = min(max(y0 + 1, 0), XH - 1);
        int x0c = min(max(x0, 0), XW - 1), x1c = min(max(x0 + 1, 0), XW - 1);
        int o00 = y0c * XW + x0c, o01 = y0c * XW + x1c;
        int o10 = y1c * XW + x0c, o11 = y1c * XW + x1c;
        for (int c = 0; c < CIN; ++c) {
            const float* xp = x + ((size_t)(n * CIN + c)) * (XH * XW);
            float v = w00 * xp[o00] + w01 * xp[o01] + w10 * xp[o10] + w11 * xp[o11];
            acc += v * w[(co * CIN + c) * NK + k];
        }
    }
    out[idx] = acc;
}

// ---------------------------------------------------------------------------
extern "C" void kernel_launch(void* const* d_in, const int* in_sizes, int n_in,
                              void* d_out, int out_size, void* d_ws, size_t ws_size,
                              hipStream_t stream) {
    const float* x    = (const float*)d_in[0];
    const float* off  = (const float*)d_in[1];
    const float* msk  = (const float*)d_in[2];
    const float* w    = (const float*)d_in[3];
    const float* bias = (const float*)d_in[4];
    float* out = (float*)d_out;

    const size_t W3_BYTES = (size_t)9 * 8 * 16 * 64 * 8 * sizeof(short); // 1179648
    const size_t XT_BYTES = (size_t)8 * XH * XW * CIN * sizeof(short);   // 16777216

    if (ws_size >= W3_BYTES + XT_BYTES) {
        short* w3 = (short*)d_ws;
        short* xT = (short*)((char*)d_ws + W3_BYTES);
        dcn_prep<<<512 + 288, 256, 0, stream>>>(x, w, xT, w3);
        dcn_fused3<<<8 * 64, 512, 0, stream>>>(xT, off, msk, w3, bias, out);
    } else if (ws_size >= W3_BYTES) {
        short* w3 = (short*)d_ws;
        dcn_wprep_v1<<<(8 * 9 * 16 * 64 * 8 + 255) / 256, 256, 0, stream>>>(w, w3);
        dcn_fused_v1<<<8 * 64, 256, 0, stream>>>(x, off, msk, w3, bias, out);
    } else {
        dcn_naive<<<(8 * COUT * XH * XW + 255) / 256, 256, 0, stream>>>(
            x, off, msk, w, bias, out);
    }
}